// Round 3
// baseline (1182.305 us; speedup 1.0000x reference)
//
#include <hip/hip_runtime.h>
#include <math.h>

#define NN 50000
#define NE 800000
#define Cc 32
#define Zz 4
#define Bb 8
#define NL 2
#define DEG_INV (1.0f/16.0f)
#define SCAN_PAD 53248  // 1024 * 52

__device__ __forceinline__ float ssp_f(float x) {
    float sp = fmaxf(x, 0.0f) + log1pf(expf(-fabsf(x)));
    return sp - 0.69314718055994530942f;
}
__device__ __forceinline__ float silu_f(float x) {
    return x / (1.0f + expf(-x));
}

// ---------------- CSR build (once per call) ----------------

__global__ void hist_kernel(const int* __restrict__ ei, int* __restrict__ counts) {
    int e = blockIdx.x * 256 + threadIdx.x;
    if (e < NE) atomicAdd(&counts[ei[NE + e]], 1);
}

// 1 block, 1024 threads: exclusive scan of counts[] -> base[NN+1], copy to cursor
// counts is zero-padded to SCAN_PAD so int4 loads are safe.
__global__ void scan_kernel(const int* __restrict__ counts,
                            int* __restrict__ base,
                            int* __restrict__ cursor) {
    __shared__ int partial[1024];
    int t = threadIdx.x;
    const int CH = 52;
    int b0 = t * CH;
    int sum = 0;
    #pragma unroll
    for (int i = 0; i < CH; i += 4) {
        int4 v = *(const int4*)(counts + b0 + i);
        sum += v.x + v.y + v.z + v.w;
    }
    partial[t] = sum;
    __syncthreads();
    for (int off = 1; off < 1024; off <<= 1) {
        int v = 0;
        if (t >= off) v = partial[t - off];
        __syncthreads();
        if (t >= off) partial[t] += v;
        __syncthreads();
    }
    int prefix = (t == 0) ? 0 : partial[t - 1];
    for (int i = b0; i < b0 + CH && i < NN; ++i) {
        base[i] = prefix;
        cursor[i] = prefix;
        prefix += counts[i];
    }
    if (t == 1023) base[NN] = partial[1023];
}

__global__ void scatter_kernel(const int* __restrict__ ei,
                               int* __restrict__ cursor,
                               int* __restrict__ perm_src,
                               int* __restrict__ perm_e) {
    int e = blockIdx.x * 256 + threadIdx.x;
    if (e >= NE) return;
    int dst = ei[NE + e];
    int pos = atomicAdd(&cursor[dst], 1);
    perm_src[pos] = ei[e];
    perm_e[pos] = e;
}

// gather emb/eattr into sorted order, once per call (sequential writes)
__global__ void permute_kernel(const int* __restrict__ perm_e,
                               const float* __restrict__ emb,
                               const float* __restrict__ eattr,
                               float* __restrict__ embS,
                               float* __restrict__ YS) {
    int pos = blockIdx.x * 256 + threadIdx.x;
    if (pos >= NE) return;
    int e = perm_e[pos];
    const float4* s4 = (const float4*)emb + (size_t)e * 2;
    float4 a = s4[0], b = s4[1];
    ((float4*)embS)[(size_t)pos * 2 + 0] = a;
    ((float4*)embS)[(size_t)pos * 2 + 1] = b;
    ((float4*)YS)[pos] = ((const float4*)eattr)[e];
}

// ---------------- per-layer kernels ----------------

// sv[n][0..31]=s, sv[n][32+c*3+i]=v
__global__ void node_pre_kernel(const float* __restrict__ x,
                                const float* __restrict__ W0,
                                const float* __restrict__ W1,
                                float* __restrict__ sv) {
    __shared__ float xs[8][128];
    int t = threadIdx.x;
    int node0 = blockIdx.x * 8;
    #pragma unroll
    for (int k = 0; k < 4; ++k) {
        int idx = t + k * 256;
        int n = idx >> 7, col = idx & 127;
        xs[n][col] = x[(size_t)(node0 + n) * 128 + col];
    }
    __syncthreads();
    int n = t >> 5, f = t & 31;
    int gn = node0 + n;
    float acc_s = 0.f, a0 = 0.f, a1 = 0.f, a2 = 0.f;
    #pragma unroll
    for (int c = 0; c < Cc; ++c) {
        float w0 = W0[c * Cc + f];
        float w1 = W1[c * Cc + f];
        acc_s = fmaf(xs[n][c], w0, acc_s);
        a0 = fmaf(xs[n][32 + c * 3 + 0], w1, a0);
        a1 = fmaf(xs[n][32 + c * 3 + 1], w1, a1);
        a2 = fmaf(xs[n][32 + c * 3 + 2], w1, a2);
    }
    float* o = sv + (size_t)gn * 128;
    o[f] = acc_s;
    o[32 + f * 3 + 0] = a0;
    o[32 + f * 3 + 1] = a1;
    o[32 + f * 3 + 2] = a2;
}

// one 32-lane group per dst node; inline h; 2-edge software pipeline; no atomics
__global__ void agg2_kernel(const int* __restrict__ base,
                            const int* __restrict__ perm_src,
                            const float* __restrict__ embS,
                            const float* __restrict__ YS,
                            const float* __restrict__ Wr1,
                            const float* __restrict__ Wr2,
                            const float* __restrict__ sv,
                            float* __restrict__ agg) {
    __shared__ float wr1s[64];
    __shared__ float wr2s[8][160];
    int t = threadIdx.x;
    if (t < 64) wr1s[t] = Wr1[t];
    for (int i = t; i < 8 * 160; i += 256) ((float*)wr2s)[i] = Wr2[i];
    __syncthreads();
    int n = blockIdx.x * 8 + (t >> 5);
    int c = t & 31;
    int jb = base[n], je = base[n + 1];

    float ms = 0.f, mv0 = 0.f, mv1 = 0.f, mv2 = 0.f;

    float h0 = 0.f, h1 = 0.f;
    float4 Ya = {0, 0, 0, 0}, Yb = {0, 0, 0, 0};
    float sa = 0.f, a0 = 0.f, a1 = 0.f, a2 = 0.f;
    float sb = 0.f, b0 = 0.f, b1 = 0.f, b2 = 0.f;

    auto load_slot = [&](int j, float& h, float4& Y,
                         float& se, float& v0, float& v1, float& v2) {
        int src = perm_src[j];
        const float4* e4 = (const float4*)embS + (size_t)j * 2;
        float4 ea = e4[0], eb = e4[1];
        Y = ((const float4*)YS)[j];
        const float* svp = sv + (size_t)src * 128;
        se = svp[c];
        v0 = svp[32 + c * 3 + 0];
        v1 = svp[32 + c * 3 + 1];
        v2 = svp[32 + c * 3 + 2];
        float hh = 0.f;
        if (c < 8) {
            float em[8] = {ea.x, ea.y, ea.z, ea.w, eb.x, eb.y, eb.z, eb.w};
            #pragma unroll
            for (int k = 0; k < 8; ++k) hh = fmaf(em[k], wr1s[k * 8 + c], hh);
            hh = silu_f(hh);
        }
        h = hh;
    };

    auto process = [&](float h, float4 Y,
                       float se, float v0, float v1, float v2) {
        float w1 = 0.f, w2 = 0.f, w3 = 0.f, w4 = 0.f, w5 = 0.f;
        #pragma unroll
        for (int k = 0; k < 8; ++k) {
            float hk = __shfl(h, k, 32);
            w1 = fmaf(hk, wr2s[k][c], w1);
            w2 = fmaf(hk, wr2s[k][32 + c], w2);
            w3 = fmaf(hk, wr2s[k][64 + c], w3);
            w4 = fmaf(hk, wr2s[k][96 + c], w4);
            w5 = fmaf(hk, wr2s[k][128 + c], w5);
        }
        float dot = v0 * Y.y + v1 * Y.z + v2 * Y.w;
        ms += w1 * se * Y.x + w4 * dot;
        float cx = v1 * Y.w - v2 * Y.z;
        float cy = v2 * Y.y - v0 * Y.w;
        float cz = v0 * Y.z - v1 * Y.y;
        mv0 += w2 * se * Y.y + w3 * v0 * Y.x + w5 * cx;
        mv1 += w2 * se * Y.z + w3 * v1 * Y.x + w5 * cy;
        mv2 += w2 * se * Y.w + w3 * v2 * Y.x + w5 * cz;
    };

    int j = jb;
    if (j     < je) load_slot(j,     h0, Ya, sa, a0, a1, a2);
    if (j + 1 < je) load_slot(j + 1, h1, Yb, sb, b0, b1, b2);
    while (j < je) {
        float ch0 = h0, cs = sa, c0 = a0, c1 = a1, c2 = a2; float4 cY = Ya;
        float ch1 = h1, ds = sb, d0 = b0, d1 = b1, d2 = b2; float4 dY = Yb;
        int rem = je - j;
        if (j + 2 < je) load_slot(j + 2, h0, Ya, sa, a0, a1, a2);
        if (j + 3 < je) load_slot(j + 3, h1, Yb, sb, b0, b1, b2);
        process(ch0, cY, cs, c0, c1, c2);
        if (rem > 1) process(ch1, dY, ds, d0, d1, d2);
        j += 2;
    }

    float* ap = agg + (size_t)n * 128;
    ap[c] = ms * DEG_INV;
    ap[32 + c * 3 + 0] = mv0 * DEG_INV;
    ap[32 + c * 3 + 1] = mv1 * DEG_INV;
    ap[32 + c * 3 + 2] = mv2 * DEG_INV;
}

// fallback (atomic) edge kernel, combined sv/agg layout
__global__ void edge_atomic_kernel(const int* __restrict__ ei,
                                   const float* __restrict__ emb,
                                   const float* __restrict__ eattr,
                                   const float* __restrict__ sv,
                                   const float* __restrict__ Wr1,
                                   const float* __restrict__ Wr2,
                                   float* __restrict__ agg) {
    int t = threadIdx.x;
    int eg = t >> 5;
    int c = t & 31;
    int e = blockIdx.x * 8 + eg;
    if (e >= NE) return;
    int src = ei[e];
    int dst = ei[NE + e];
    float h = 0.f;
    if (c < 8) {
        #pragma unroll
        for (int k = 0; k < 8; ++k)
            h = fmaf(emb[e * 8 + k], Wr1[k * 8 + c], h);
        h = silu_f(h);
    }
    float w1 = 0.f, w2 = 0.f, w3 = 0.f, w4 = 0.f, w5 = 0.f;
    #pragma unroll
    for (int j = 0; j < 8; ++j) {
        float hj = __shfl(h, j, 32);
        const float* wr = Wr2 + j * 160;
        w1 = fmaf(hj, wr[c], w1);
        w2 = fmaf(hj, wr[32 + c], w2);
        w3 = fmaf(hj, wr[64 + c], w3);
        w4 = fmaf(hj, wr[96 + c], w4);
        w5 = fmaf(hj, wr[128 + c], w5);
    }
    float Y0  = eattr[e * 4 + 0];
    float Yv0 = eattr[e * 4 + 1];
    float Yv1 = eattr[e * 4 + 2];
    float Yv2 = eattr[e * 4 + 3];
    const float* svp = sv + (size_t)src * 128;
    float se  = svp[c];
    float ve0 = svp[32 + c * 3 + 0];
    float ve1 = svp[32 + c * 3 + 1];
    float ve2 = svp[32 + c * 3 + 2];
    float dot = ve0 * Yv0 + ve1 * Yv1 + ve2 * Yv2;
    float msg = (w1 * se * Y0 + w4 * dot) * DEG_INV;
    float cx = ve1 * Yv2 - ve2 * Yv1;
    float cy = ve2 * Yv0 - ve0 * Yv2;
    float cz = ve0 * Yv1 - ve1 * Yv0;
    float mv0 = (w2 * se * Yv0 + w3 * ve0 * Y0 + w5 * cx) * DEG_INV;
    float mv1 = (w2 * se * Yv1 + w3 * ve1 * Y0 + w5 * cy) * DEG_INV;
    float mv2 = (w2 * se * Yv2 + w3 * ve2 * Y0 + w5 * cz) * DEG_INV;
    float* ap = agg + (size_t)dst * 128;
    atomicAdd(&ap[c], msg);
    atomicAdd(&ap[32 + c * 3 + 0], mv0);
    atomicAdd(&ap[32 + c * 3 + 1], mv1);
    atomicAdd(&ap[32 + c * 3 + 2], mv2);
}

__global__ void node_post_kernel(float* __restrict__ x,
                                 const float* __restrict__ attrs,
                                 const float* __restrict__ agg,
                                 const float* __restrict__ Ws,
                                 const float* __restrict__ Wv,
                                 const float* __restrict__ Wsc_s,
                                 const float* __restrict__ Wsc_v) {
    __shared__ float shx[8][128];
    __shared__ float sha[8][128];
    int t = threadIdx.x;
    int node0 = blockIdx.x * 8;
    #pragma unroll
    for (int k = 0; k < 4; ++k) {
        int idx = t + k * 256;
        int n = idx >> 7, col = idx & 127;
        int gn = node0 + n;
        shx[n][col] = x[(size_t)gn * 128 + col];
        sha[n][col] = agg[(size_t)gn * 128 + col];
    }
    __syncthreads();
    int n = t >> 5, f = t & 31;
    int gn = node0 + n;

    float az0 = attrs[gn * 4 + 0], az1 = attrs[gn * 4 + 1];
    float az2 = attrs[gn * 4 + 2], az3 = attrs[gn * 4 + 3];

    float os0 = 0.f, os1 = 0.f;
    float ov0 = 0.f, ov1 = 0.f, ov2 = 0.f;

    #pragma unroll 4
    for (int c = 0; c < Cc; ++c) {
        float as = sha[n][c];
        os0 = fmaf(as, Ws[c * 64 + f], os0);
        os1 = fmaf(as, Ws[c * 64 + 32 + f], os1);

        float av0 = sha[n][32 + c * 3 + 0];
        float av1 = sha[n][32 + c * 3 + 1];
        float av2 = sha[n][32 + c * 3 + 2];
        float wv = Wv[c * 32 + f];
        ov0 = fmaf(av0, wv, ov0);
        ov1 = fmaf(av1, wv, ov1);
        ov2 = fmaf(av2, wv, ov2);

        float sc  = shx[n][c];
        float vi0 = shx[n][32 + c * 3 + 0];
        float vi1 = shx[n][32 + c * 3 + 1];
        float vi2 = shx[n][32 + c * 3 + 2];

        #pragma unroll
        for (int z = 0; z < 4; ++z) {
            float azv = (z == 0) ? az0 : (z == 1) ? az1 : (z == 2) ? az2 : az3;
            int cz = c * 4 + z;
            float sa = sc * azv;
            os0 = fmaf(sa, Wsc_s[cz * 64 + f], os0);
            os1 = fmaf(sa, Wsc_s[cz * 64 + 32 + f], os1);
            float va = azv * Wsc_v[cz * 32 + f];
            ov0 = fmaf(vi0, va, ov0);
            ov1 = fmaf(vi1, va, ov1);
            ov2 = fmaf(vi2, va, ov2);
        }
    }
    float feat = ssp_f(os0);
    float gate = ssp_f(os1);
    float* xp = x + (size_t)gn * 128;
    xp[f] += feat;
    xp[32 + f * 3 + 0] += ov0 * gate;
    xp[32 + f * 3 + 1] += ov1 * gate;
    xp[32 + f * 3 + 2] += ov2 * gate;
}

extern "C" void kernel_launch(void* const* d_in, const int* in_sizes, int n_in,
                              void* d_out, int out_size, void* d_ws, size_t ws_size,
                              hipStream_t stream) {
    const float* node_features  = (const float*)d_in[0];
    const float* node_attrs     = (const float*)d_in[1];
    const int*   edge_index     = (const int*)d_in[2];
    const float* edge_embedding = (const float*)d_in[3];
    const float* edge_attrs     = (const float*)d_in[4];
    const float* W0    = (const float*)d_in[5];
    const float* W1    = (const float*)d_in[6];
    const float* Wr1   = (const float*)d_in[7];
    const float* Wr2   = (const float*)d_in[8];
    const float* Ws    = (const float*)d_in[9];
    const float* Wv    = (const float*)d_in[10];
    const float* Wsc_s = (const float*)d_in[11];
    const float* Wsc_v = (const float*)d_in[12];

    float* x = (float*)d_out;

    // float arrays first (16B alignment for float4), then int arrays
    float* ws = (float*)d_ws;
    float* sv   = ws;                                 // NN*128
    float* agg  = sv + (size_t)NN * 128;              // NN*128
    float* embS = agg + (size_t)NN * 128;             // NE*8
    float* YS   = embS + (size_t)NE * 8;              // NE*4
    int* counts   = (int*)(YS + (size_t)NE * 4);      // SCAN_PAD
    int* base     = counts + SCAN_PAD;                // NN+1
    int* cursor   = base + NN + 1;                    // NN
    int* perm_src = cursor + NN;                      // NE
    int* perm_e   = perm_src + NE;                    // NE
    size_t needed = ((char*)(perm_e + NE)) - (char*)d_ws;

    hipMemcpyAsync(x, node_features, (size_t)NN * 128 * sizeof(float),
                   hipMemcpyDeviceToDevice, stream);

    bool use_sorted = ws_size >= needed;

    if (use_sorted) {
        hipMemsetAsync(counts, 0, SCAN_PAD * sizeof(int), stream);
        hist_kernel<<<NE / 256, 256, 0, stream>>>(edge_index, counts);
        scan_kernel<<<1, 1024, 0, stream>>>(counts, base, cursor);
        scatter_kernel<<<NE / 256, 256, 0, stream>>>(edge_index, cursor, perm_src, perm_e);
        permute_kernel<<<NE / 256, 256, 0, stream>>>(perm_e, edge_embedding, edge_attrs, embS, YS);

        for (int l = 0; l < NL; ++l) {
            node_pre_kernel<<<NN / 8, 256, 0, stream>>>(
                x, W0 + l * Cc * Cc, W1 + l * Cc * Cc, sv);
            agg2_kernel<<<NN / 8, 256, 0, stream>>>(
                base, perm_src, embS, YS,
                Wr1 + l * Bb * Bb, Wr2 + l * Bb * 5 * Cc, sv, agg);
            node_post_kernel<<<NN / 8, 256, 0, stream>>>(
                x, node_attrs, agg,
                Ws + l * Cc * 2 * Cc, Wv + l * Cc * Cc,
                Wsc_s + l * Cc * Zz * 2 * Cc, Wsc_v + l * Cc * Zz * Cc);
        }
    } else {
        for (int l = 0; l < NL; ++l) {
            hipMemsetAsync(agg, 0, (size_t)NN * 128 * sizeof(float), stream);
            node_pre_kernel<<<NN / 8, 256, 0, stream>>>(
                x, W0 + l * Cc * Cc, W1 + l * Cc * Cc, sv);
            edge_atomic_kernel<<<NE / 8, 256, 0, stream>>>(
                edge_index, edge_embedding, edge_attrs, sv,
                Wr1 + l * Bb * Bb, Wr2 + l * Bb * 5 * Cc, agg);
            node_post_kernel<<<NN / 8, 256, 0, stream>>>(
                x, node_attrs, agg,
                Ws + l * Cc * 2 * Cc, Wv + l * Cc * Cc,
                Wsc_s + l * Cc * Zz * 2 * Cc, Wsc_v + l * Cc * Zz * Cc);
        }
    }
}

// Round 4
// 667.043 us; speedup vs baseline: 1.7725x; 1.7725x over previous
//
#include <hip/hip_runtime.h>
#include <math.h>

#define NN 50000
#define NE 800000
#define Cc 32
#define Zz 4
#define Bb 8
#define NL 2
#define DEG_INV (1.0f/16.0f)
#define SCAN_PAD 53248  // 1024 * 52

__device__ __forceinline__ float ssp_f(float x) {
    float sp = fmaxf(x, 0.0f) + log1pf(expf(-fabsf(x)));
    return sp - 0.69314718055994530942f;
}
__device__ __forceinline__ float silu_f(float x) {
    return x / (1.0f + expf(-x));
}

// ---------------- CSR build (once per call) ----------------

__global__ void hist_kernel(const int* __restrict__ ei, int* __restrict__ counts) {
    int e = blockIdx.x * 256 + threadIdx.x;
    if (e < NE) atomicAdd(&counts[ei[NE + e]], 1);
}

// 1 block, 1024 threads: exclusive scan of counts[] -> base[NN+1], copy to cursor
// counts is zero-padded to SCAN_PAD so int4 loads are safe.
__global__ void scan_kernel(const int* __restrict__ counts,
                            int* __restrict__ base,
                            int* __restrict__ cursor) {
    __shared__ int partial[1024];
    int t = threadIdx.x;
    const int CH = 52;
    int b0 = t * CH;
    int sum = 0;
    #pragma unroll
    for (int i = 0; i < CH; i += 4) {
        int4 v = *(const int4*)(counts + b0 + i);
        sum += v.x + v.y + v.z + v.w;
    }
    partial[t] = sum;
    __syncthreads();
    for (int off = 1; off < 1024; off <<= 1) {
        int v = 0;
        if (t >= off) v = partial[t - off];
        __syncthreads();
        if (t >= off) partial[t] += v;
        __syncthreads();
    }
    int prefix = (t == 0) ? 0 : partial[t - 1];
    for (int i = b0; i < b0 + CH && i < NN; ++i) {
        base[i] = prefix;
        cursor[i] = prefix;
        prefix += counts[i];
    }
    if (t == 1023) base[NN] = partial[1023];
}

__global__ void scatter_kernel(const int* __restrict__ ei,
                               int* __restrict__ cursor,
                               int* __restrict__ perm_src,
                               int* __restrict__ perm_e) {
    int e = blockIdx.x * 256 + threadIdx.x;
    if (e >= NE) return;
    int dst = ei[NE + e];
    int pos = atomicAdd(&cursor[dst], 1);
    perm_src[pos] = ei[e];
    perm_e[pos] = e;
}

// one-time: gather emb/eattr into sorted order AND precompute
// h[l] = silu(emb @ Wr1[l]) for both layers (sequential writes)
__global__ void permute_h_kernel(const int* __restrict__ perm_e,
                                 const float* __restrict__ emb,
                                 const float* __restrict__ eattr,
                                 const float* __restrict__ Wr1,   // [2][8][8]
                                 float* __restrict__ hS0,
                                 float* __restrict__ hS1,
                                 float* __restrict__ YS) {
    __shared__ float wr1s[2][64];
    int t = threadIdx.x;
    if (t < 128) ((float*)wr1s)[t] = Wr1[t];
    __syncthreads();
    int pos = blockIdx.x * 256 + t;
    if (pos >= NE) return;
    int e = perm_e[pos];
    const float4* s4 = (const float4*)emb + (size_t)e * 2;
    float4 a = s4[0], b = s4[1];
    float em[8] = {a.x, a.y, a.z, a.w, b.x, b.y, b.z, b.w};
    float h0[8], h1[8];
    #pragma unroll
    for (int j = 0; j < 8; ++j) {
        float acc0 = 0.f, acc1 = 0.f;
        #pragma unroll
        for (int k = 0; k < 8; ++k) {
            acc0 = fmaf(em[k], wr1s[0][k * 8 + j], acc0);
            acc1 = fmaf(em[k], wr1s[1][k * 8 + j], acc1);
        }
        h0[j] = silu_f(acc0);
        h1[j] = silu_f(acc1);
    }
    float4* o0 = (float4*)(hS0 + (size_t)pos * 8);
    o0[0] = make_float4(h0[0], h0[1], h0[2], h0[3]);
    o0[1] = make_float4(h0[4], h0[5], h0[6], h0[7]);
    float4* o1 = (float4*)(hS1 + (size_t)pos * 8);
    o1[0] = make_float4(h1[0], h1[1], h1[2], h1[3]);
    o1[1] = make_float4(h1[4], h1[5], h1[6], h1[7]);
    ((float4*)YS)[pos] = ((const float4*)eattr)[e];
}

// ---------------- per-layer kernels ----------------

// sv[n][0..31]=s, sv[n][32+c*3+i]=v
__global__ void node_pre_kernel(const float* __restrict__ x,
                                const float* __restrict__ W0,
                                const float* __restrict__ W1,
                                float* __restrict__ sv) {
    __shared__ float xs[8][128];
    int t = threadIdx.x;
    int node0 = blockIdx.x * 8;
    #pragma unroll
    for (int k = 0; k < 4; ++k) {
        int idx = t + k * 256;
        int n = idx >> 7, col = idx & 127;
        xs[n][col] = x[(size_t)(node0 + n) * 128 + col];
    }
    __syncthreads();
    int n = t >> 5, f = t & 31;
    int gn = node0 + n;
    float acc_s = 0.f, a0 = 0.f, a1 = 0.f, a2 = 0.f;
    #pragma unroll
    for (int c = 0; c < Cc; ++c) {
        float w0 = W0[c * Cc + f];
        float w1 = W1[c * Cc + f];
        acc_s = fmaf(xs[n][c], w0, acc_s);
        a0 = fmaf(xs[n][32 + c * 3 + 0], w1, a0);
        a1 = fmaf(xs[n][32 + c * 3 + 1], w1, a1);
        a2 = fmaf(xs[n][32 + c * 3 + 2], w1, a2);
    }
    float* o = sv + (size_t)gn * 128;
    o[f] = acc_s;
    o[32 + f * 3 + 0] = a0;
    o[32 + f * 3 + 1] = a1;
    o[32 + f * 3 + 2] = a2;
}

// one 32-lane group per dst node; walks its contiguous CSR segment; no atomics
// (exact round-2 structure that measured 119 us)
__global__ void agg_kernel(const int* __restrict__ base,
                           const int* __restrict__ perm_src,
                           const float* __restrict__ hS,
                           const float* __restrict__ YS,
                           const float* __restrict__ sv,
                           const float* __restrict__ Wr2,
                           float* __restrict__ agg) {
    __shared__ float wr2s[8][160];
    int t = threadIdx.x;
    for (int i = t; i < 8 * 160; i += 256) ((float*)wr2s)[i] = Wr2[i];
    __syncthreads();
    int n = blockIdx.x * 8 + (t >> 5);
    int c = t & 31;
    int jb = base[n], je = base[n + 1];
    float ms = 0.f, mv0 = 0.f, mv1 = 0.f, mv2 = 0.f;
    for (int j = jb; j < je; ++j) {
        int src = perm_src[j];
        const float4* h4 = (const float4*)(hS + (size_t)j * 8);
        float4 ha = h4[0], hb = h4[1];
        float4 Y = ((const float4*)YS)[j];
        float h[8] = {ha.x, ha.y, ha.z, ha.w, hb.x, hb.y, hb.z, hb.w};
        float w1 = 0.f, w2 = 0.f, w3 = 0.f, w4 = 0.f, w5 = 0.f;
        #pragma unroll
        for (int k = 0; k < 8; ++k) {
            float hk = h[k];
            w1 = fmaf(hk, wr2s[k][c], w1);
            w2 = fmaf(hk, wr2s[k][32 + c], w2);
            w3 = fmaf(hk, wr2s[k][64 + c], w3);
            w4 = fmaf(hk, wr2s[k][96 + c], w4);
            w5 = fmaf(hk, wr2s[k][128 + c], w5);
        }
        const float* svp = sv + (size_t)src * 128;
        float se  = svp[c];
        float ve0 = svp[32 + c * 3 + 0];
        float ve1 = svp[32 + c * 3 + 1];
        float ve2 = svp[32 + c * 3 + 2];

        float dot = ve0 * Y.y + ve1 * Y.z + ve2 * Y.w;
        ms += w1 * se * Y.x + w4 * dot;

        float cx = ve1 * Y.w - ve2 * Y.z;
        float cy = ve2 * Y.y - ve0 * Y.w;
        float cz = ve0 * Y.z - ve1 * Y.y;

        mv0 += w2 * se * Y.y + w3 * ve0 * Y.x + w5 * cx;
        mv1 += w2 * se * Y.z + w3 * ve1 * Y.x + w5 * cy;
        mv2 += w2 * se * Y.w + w3 * ve2 * Y.x + w5 * cz;
    }
    float* ap = agg + (size_t)n * 128;
    ap[c] = ms * DEG_INV;
    ap[32 + c * 3 + 0] = mv0 * DEG_INV;
    ap[32 + c * 3 + 1] = mv1 * DEG_INV;
    ap[32 + c * 3 + 2] = mv2 * DEG_INV;
}

// fallback (atomic) edge kernel, combined sv/agg layout
__global__ void edge_atomic_kernel(const int* __restrict__ ei,
                                   const float* __restrict__ emb,
                                   const float* __restrict__ eattr,
                                   const float* __restrict__ sv,
                                   const float* __restrict__ Wr1,
                                   const float* __restrict__ Wr2,
                                   float* __restrict__ agg) {
    int t = threadIdx.x;
    int eg = t >> 5;
    int c = t & 31;
    int e = blockIdx.x * 8 + eg;
    if (e >= NE) return;
    int src = ei[e];
    int dst = ei[NE + e];
    float h = 0.f;
    if (c < 8) {
        #pragma unroll
        for (int k = 0; k < 8; ++k)
            h = fmaf(emb[e * 8 + k], Wr1[k * 8 + c], h);
        h = silu_f(h);
    }
    float w1 = 0.f, w2 = 0.f, w3 = 0.f, w4 = 0.f, w5 = 0.f;
    #pragma unroll
    for (int j = 0; j < 8; ++j) {
        float hj = __shfl(h, j, 32);
        const float* wr = Wr2 + j * 160;
        w1 = fmaf(hj, wr[c], w1);
        w2 = fmaf(hj, wr[32 + c], w2);
        w3 = fmaf(hj, wr[64 + c], w3);
        w4 = fmaf(hj, wr[96 + c], w4);
        w5 = fmaf(hj, wr[128 + c], w5);
    }
    float Y0  = eattr[e * 4 + 0];
    float Yv0 = eattr[e * 4 + 1];
    float Yv1 = eattr[e * 4 + 2];
    float Yv2 = eattr[e * 4 + 3];
    const float* svp = sv + (size_t)src * 128;
    float se  = svp[c];
    float ve0 = svp[32 + c * 3 + 0];
    float ve1 = svp[32 + c * 3 + 1];
    float ve2 = svp[32 + c * 3 + 2];
    float dot = ve0 * Yv0 + ve1 * Yv1 + ve2 * Yv2;
    float msg = (w1 * se * Y0 + w4 * dot) * DEG_INV;
    float cx = ve1 * Yv2 - ve2 * Yv1;
    float cy = ve2 * Yv0 - ve0 * Yv2;
    float cz = ve0 * Yv1 - ve1 * Yv0;
    float mv0 = (w2 * se * Yv0 + w3 * ve0 * Y0 + w5 * cx) * DEG_INV;
    float mv1 = (w2 * se * Yv1 + w3 * ve1 * Y0 + w5 * cy) * DEG_INV;
    float mv2 = (w2 * se * Yv2 + w3 * ve2 * Y0 + w5 * cz) * DEG_INV;
    float* ap = agg + (size_t)dst * 128;
    atomicAdd(&ap[c], msg);
    atomicAdd(&ap[32 + c * 3 + 0], mv0);
    atomicAdd(&ap[32 + c * 3 + 1], mv1);
    atomicAdd(&ap[32 + c * 3 + 2], mv2);
}

__global__ void node_post_kernel(float* __restrict__ x,
                                 const float* __restrict__ attrs,
                                 const float* __restrict__ agg,
                                 const float* __restrict__ Ws,
                                 const float* __restrict__ Wv,
                                 const float* __restrict__ Wsc_s,
                                 const float* __restrict__ Wsc_v) {
    __shared__ float shx[8][128];
    __shared__ float sha[8][128];
    int t = threadIdx.x;
    int node0 = blockIdx.x * 8;
    #pragma unroll
    for (int k = 0; k < 4; ++k) {
        int idx = t + k * 256;
        int n = idx >> 7, col = idx & 127;
        int gn = node0 + n;
        shx[n][col] = x[(size_t)gn * 128 + col];
        sha[n][col] = agg[(size_t)gn * 128 + col];
    }
    __syncthreads();
    int n = t >> 5, f = t & 31;
    int gn = node0 + n;

    float az0 = attrs[gn * 4 + 0], az1 = attrs[gn * 4 + 1];
    float az2 = attrs[gn * 4 + 2], az3 = attrs[gn * 4 + 3];

    float os0 = 0.f, os1 = 0.f;
    float ov0 = 0.f, ov1 = 0.f, ov2 = 0.f;

    #pragma unroll 4
    for (int c = 0; c < Cc; ++c) {
        float as = sha[n][c];
        os0 = fmaf(as, Ws[c * 64 + f], os0);
        os1 = fmaf(as, Ws[c * 64 + 32 + f], os1);

        float av0 = sha[n][32 + c * 3 + 0];
        float av1 = sha[n][32 + c * 3 + 1];
        float av2 = sha[n][32 + c * 3 + 2];
        float wv = Wv[c * 32 + f];
        ov0 = fmaf(av0, wv, ov0);
        ov1 = fmaf(av1, wv, ov1);
        ov2 = fmaf(av2, wv, ov2);

        float sc  = shx[n][c];
        float vi0 = shx[n][32 + c * 3 + 0];
        float vi1 = shx[n][32 + c * 3 + 1];
        float vi2 = shx[n][32 + c * 3 + 2];

        #pragma unroll
        for (int z = 0; z < 4; ++z) {
            float azv = (z == 0) ? az0 : (z == 1) ? az1 : (z == 2) ? az2 : az3;
            int cz = c * 4 + z;
            float sa = sc * azv;
            os0 = fmaf(sa, Wsc_s[cz * 64 + f], os0);
            os1 = fmaf(sa, Wsc_s[cz * 64 + 32 + f], os1);
            float va = azv * Wsc_v[cz * 32 + f];
            ov0 = fmaf(vi0, va, ov0);
            ov1 = fmaf(vi1, va, ov1);
            ov2 = fmaf(vi2, va, ov2);
        }
    }
    float feat = ssp_f(os0);
    float gate = ssp_f(os1);
    float* xp = x + (size_t)gn * 128;
    xp[f] += feat;
    xp[32 + f * 3 + 0] += ov0 * gate;
    xp[32 + f * 3 + 1] += ov1 * gate;
    xp[32 + f * 3 + 2] += ov2 * gate;
}

extern "C" void kernel_launch(void* const* d_in, const int* in_sizes, int n_in,
                              void* d_out, int out_size, void* d_ws, size_t ws_size,
                              hipStream_t stream) {
    const float* node_features  = (const float*)d_in[0];
    const float* node_attrs     = (const float*)d_in[1];
    const int*   edge_index     = (const int*)d_in[2];
    const float* edge_embedding = (const float*)d_in[3];
    const float* edge_attrs     = (const float*)d_in[4];
    const float* W0    = (const float*)d_in[5];
    const float* W1    = (const float*)d_in[6];
    const float* Wr1   = (const float*)d_in[7];
    const float* Wr2   = (const float*)d_in[8];
    const float* Ws    = (const float*)d_in[9];
    const float* Wv    = (const float*)d_in[10];
    const float* Wsc_s = (const float*)d_in[11];
    const float* Wsc_v = (const float*)d_in[12];

    float* x = (float*)d_out;

    // float arrays first (16B alignment for float4), then int arrays
    float* ws = (float*)d_ws;
    float* sv   = ws;                                 // NN*128
    float* agg  = sv + (size_t)NN * 128;              // NN*128
    float* hS0  = agg + (size_t)NN * 128;             // NE*8
    float* hS1  = hS0 + (size_t)NE * 8;               // NE*8
    float* YS   = hS1 + (size_t)NE * 8;               // NE*4
    int* counts   = (int*)(YS + (size_t)NE * 4);      // SCAN_PAD
    int* base     = counts + SCAN_PAD;                // NN+1
    int* cursor   = base + NN + 1;                    // NN
    int* perm_src = cursor + NN;                      // NE
    int* perm_e   = perm_src + NE;                    // NE
    size_t needed = ((char*)(perm_e + NE)) - (char*)d_ws;

    hipMemcpyAsync(x, node_features, (size_t)NN * 128 * sizeof(float),
                   hipMemcpyDeviceToDevice, stream);

    bool use_sorted = ws_size >= needed;

    if (use_sorted) {
        hipMemsetAsync(counts, 0, SCAN_PAD * sizeof(int), stream);
        hist_kernel<<<NE / 256, 256, 0, stream>>>(edge_index, counts);
        scan_kernel<<<1, 1024, 0, stream>>>(counts, base, cursor);
        scatter_kernel<<<NE / 256, 256, 0, stream>>>(edge_index, cursor, perm_src, perm_e);
        permute_h_kernel<<<NE / 256, 256, 0, stream>>>(
            perm_e, edge_embedding, edge_attrs, Wr1, hS0, hS1, YS);

        for (int l = 0; l < NL; ++l) {
            node_pre_kernel<<<NN / 8, 256, 0, stream>>>(
                x, W0 + l * Cc * Cc, W1 + l * Cc * Cc, sv);
            agg_kernel<<<NN / 8, 256, 0, stream>>>(
                base, perm_src, (l == 0) ? hS0 : hS1, YS, sv,
                Wr2 + l * Bb * 5 * Cc, agg);
            node_post_kernel<<<NN / 8, 256, 0, stream>>>(
                x, node_attrs, agg,
                Ws + l * Cc * 2 * Cc, Wv + l * Cc * Cc,
                Wsc_s + l * Cc * Zz * 2 * Cc, Wsc_v + l * Cc * Zz * Cc);
        }
    } else {
        for (int l = 0; l < NL; ++l) {
            hipMemsetAsync(agg, 0, (size_t)NN * 128 * sizeof(float), stream);
            node_pre_kernel<<<NN / 8, 256, 0, stream>>>(
                x, W0 + l * Cc * Cc, W1 + l * Cc * Cc, sv);
            edge_atomic_kernel<<<NE / 8, 256, 0, stream>>>(
                edge_index, edge_embedding, edge_attrs, sv,
                Wr1, Wr2 + l * Bb * 5 * Cc, agg);
            node_post_kernel<<<NN / 8, 256, 0, stream>>>(
                x, node_attrs, agg,
                Ws + l * Cc * 2 * Cc, Wv + l * Cc * Cc,
                Wsc_s + l * Cc * Zz * 2 * Cc, Wsc_v + l * Cc * Zz * Cc);
        }
    }
}

// Round 5
// 602.600 us; speedup vs baseline: 1.9620x; 1.1069x over previous
//
#include <hip/hip_runtime.h>
#include <math.h>

#define NN 50000
#define NE 800000
#define Cc 32
#define Zz 4
#define Bb 8
#define NL 2
#define DEG_INV (1.0f/16.0f)
#define SCAN_PAD 53248  // 1024 * 52

__device__ __forceinline__ float ssp_f(float x) {
    float sp = fmaxf(x, 0.0f) + log1pf(expf(-fabsf(x)));
    return sp - 0.69314718055994530942f;
}
__device__ __forceinline__ float silu_f(float x) {
    return x / (1.0f + expf(-x));
}

// ---------------- CSR build (once per call) ----------------

__global__ void hist_kernel(const int* __restrict__ ei, int* __restrict__ counts) {
    int e = blockIdx.x * 256 + threadIdx.x;
    if (e < NE) atomicAdd(&counts[ei[NE + e]], 1);
}

// 1 block, 1024 threads: exclusive scan of counts[] -> base[NN+1], copy to cursor
__global__ void scan_kernel(const int* __restrict__ counts,
                            int* __restrict__ base,
                            int* __restrict__ cursor) {
    __shared__ int partial[1024];
    int t = threadIdx.x;
    const int CH = 52;
    int b0 = t * CH;
    int sum = 0;
    #pragma unroll
    for (int i = 0; i < CH; i += 4) {
        int4 v = *(const int4*)(counts + b0 + i);
        sum += v.x + v.y + v.z + v.w;
    }
    partial[t] = sum;
    __syncthreads();
    for (int off = 1; off < 1024; off <<= 1) {
        int v = 0;
        if (t >= off) v = partial[t - off];
        __syncthreads();
        if (t >= off) partial[t] += v;
        __syncthreads();
    }
    int prefix = (t == 0) ? 0 : partial[t - 1];
    for (int i = b0; i < b0 + CH && i < NN; ++i) {
        base[i] = prefix;
        cursor[i] = prefix;
        prefix += counts[i];
    }
    if (t == 1023) base[NN] = partial[1023];
}

// fused scatter + permute + h-precompute (both layers).
// Sequential reads of ei/emb/eattr; scattered writes to sorted slots.
__global__ void scatter_h_kernel(const int* __restrict__ ei,
                                 const float* __restrict__ emb,
                                 const float* __restrict__ eattr,
                                 const float* __restrict__ Wr1,   // [2][8][8]
                                 int* __restrict__ cursor,
                                 int* __restrict__ perm_src,
                                 float* __restrict__ hS0,
                                 float* __restrict__ hS1,
                                 float* __restrict__ YS) {
    __shared__ float wr1s[2][64];
    int t = threadIdx.x;
    if (t < 128) ((float*)wr1s)[t] = Wr1[t];
    __syncthreads();
    int e = blockIdx.x * 256 + t;
    if (e >= NE) return;
    int dst = ei[NE + e];
    int pos = atomicAdd(&cursor[dst], 1);
    perm_src[pos] = ei[e];

    const float4* s4 = (const float4*)emb + (size_t)e * 2;
    float4 a = s4[0], b = s4[1];
    float em[8] = {a.x, a.y, a.z, a.w, b.x, b.y, b.z, b.w};
    float h0[8], h1[8];
    #pragma unroll
    for (int j = 0; j < 8; ++j) {
        float acc0 = 0.f, acc1 = 0.f;
        #pragma unroll
        for (int k = 0; k < 8; ++k) {
            acc0 = fmaf(em[k], wr1s[0][k * 8 + j], acc0);
            acc1 = fmaf(em[k], wr1s[1][k * 8 + j], acc1);
        }
        h0[j] = silu_f(acc0);
        h1[j] = silu_f(acc1);
    }
    float4* o0 = (float4*)(hS0 + (size_t)pos * 8);
    o0[0] = make_float4(h0[0], h0[1], h0[2], h0[3]);
    o0[1] = make_float4(h0[4], h0[5], h0[6], h0[7]);
    float4* o1 = (float4*)(hS1 + (size_t)pos * 8);
    o1[0] = make_float4(h1[0], h1[1], h1[2], h1[3]);
    o1[1] = make_float4(h1[4], h1[5], h1[6], h1[7]);
    ((float4*)YS)[pos] = ((const float4*)eattr)[e];
}

// ---------------- per-layer kernels ----------------

// fused: x = node_features (copy) + sv = pre(x)
__global__ void init_kernel(const float* __restrict__ nf,
                            const float* __restrict__ W0,
                            const float* __restrict__ W1,
                            float* __restrict__ x,
                            float* __restrict__ sv) {
    __shared__ float xs[8][128];
    int t = threadIdx.x;
    int node0 = blockIdx.x * 8;
    #pragma unroll
    for (int k = 0; k < 4; ++k) {
        int idx = t + k * 256;
        int n = idx >> 7, col = idx & 127;
        float val = nf[(size_t)(node0 + n) * 128 + col];
        xs[n][col] = val;
        x[(size_t)(node0 + n) * 128 + col] = val;
    }
    __syncthreads();
    int n = t >> 5, f = t & 31;
    int gn = node0 + n;
    float acc_s = 0.f, a0 = 0.f, a1 = 0.f, a2 = 0.f;
    #pragma unroll
    for (int c = 0; c < Cc; ++c) {
        float w0 = W0[c * Cc + f];
        float w1 = W1[c * Cc + f];
        acc_s = fmaf(xs[n][c], w0, acc_s);
        a0 = fmaf(xs[n][32 + c * 3 + 0], w1, a0);
        a1 = fmaf(xs[n][32 + c * 3 + 1], w1, a1);
        a2 = fmaf(xs[n][32 + c * 3 + 2], w1, a2);
    }
    float* o = sv + (size_t)gn * 128;
    o[f] = acc_s;
    o[32 + f * 3 + 0] = a0;
    o[32 + f * 3 + 1] = a1;
    o[32 + f * 3 + 2] = a2;
}

#define PROC_EDGE(ha, hb, Yv, se, v0, v1, v2)                                \
    do {                                                                     \
        float hh0 = ha.x, hh1 = ha.y, hh2 = ha.z, hh3 = ha.w;                \
        float hh4 = hb.x, hh5 = hb.y, hh6 = hb.z, hh7 = hb.w;                \
        float w1 = 0.f, w2 = 0.f, w3 = 0.f, w4 = 0.f, w5 = 0.f;              \
        w1 = fmaf(hh0, wr2s[0][c], w1); w2 = fmaf(hh0, wr2s[0][32 + c], w2); \
        w3 = fmaf(hh0, wr2s[0][64 + c], w3); w4 = fmaf(hh0, wr2s[0][96 + c], w4); \
        w5 = fmaf(hh0, wr2s[0][128 + c], w5);                                \
        w1 = fmaf(hh1, wr2s[1][c], w1); w2 = fmaf(hh1, wr2s[1][32 + c], w2); \
        w3 = fmaf(hh1, wr2s[1][64 + c], w3); w4 = fmaf(hh1, wr2s[1][96 + c], w4); \
        w5 = fmaf(hh1, wr2s[1][128 + c], w5);                                \
        w1 = fmaf(hh2, wr2s[2][c], w1); w2 = fmaf(hh2, wr2s[2][32 + c], w2); \
        w3 = fmaf(hh2, wr2s[2][64 + c], w3); w4 = fmaf(hh2, wr2s[2][96 + c], w4); \
        w5 = fmaf(hh2, wr2s[2][128 + c], w5);                                \
        w1 = fmaf(hh3, wr2s[3][c], w1); w2 = fmaf(hh3, wr2s[3][32 + c], w2); \
        w3 = fmaf(hh3, wr2s[3][64 + c], w3); w4 = fmaf(hh3, wr2s[3][96 + c], w4); \
        w5 = fmaf(hh3, wr2s[3][128 + c], w5);                                \
        w1 = fmaf(hh4, wr2s[4][c], w1); w2 = fmaf(hh4, wr2s[4][32 + c], w2); \
        w3 = fmaf(hh4, wr2s[4][64 + c], w3); w4 = fmaf(hh4, wr2s[4][96 + c], w4); \
        w5 = fmaf(hh4, wr2s[4][128 + c], w5);                                \
        w1 = fmaf(hh5, wr2s[5][c], w1); w2 = fmaf(hh5, wr2s[5][32 + c], w2); \
        w3 = fmaf(hh5, wr2s[5][64 + c], w3); w4 = fmaf(hh5, wr2s[5][96 + c], w4); \
        w5 = fmaf(hh5, wr2s[5][128 + c], w5);                                \
        w1 = fmaf(hh6, wr2s[6][c], w1); w2 = fmaf(hh6, wr2s[6][32 + c], w2); \
        w3 = fmaf(hh6, wr2s[6][64 + c], w3); w4 = fmaf(hh6, wr2s[6][96 + c], w4); \
        w5 = fmaf(hh6, wr2s[6][128 + c], w5);                                \
        w1 = fmaf(hh7, wr2s[7][c], w1); w2 = fmaf(hh7, wr2s[7][32 + c], w2); \
        w3 = fmaf(hh7, wr2s[7][64 + c], w3); w4 = fmaf(hh7, wr2s[7][96 + c], w4); \
        w5 = fmaf(hh7, wr2s[7][128 + c], w5);                                \
        float dot = v0 * Yv.y + v1 * Yv.z + v2 * Yv.w;                       \
        ms += w1 * se * Yv.x + w4 * dot;                                     \
        float cx = v1 * Yv.w - v2 * Yv.z;                                    \
        float cy = v2 * Yv.y - v0 * Yv.w;                                    \
        float cz = v0 * Yv.z - v1 * Yv.y;                                    \
        mv0 += w2 * se * Yv.y + w3 * v0 * Yv.x + w5 * cx;                    \
        mv1 += w2 * se * Yv.z + w3 * v1 * Yv.x + w5 * cy;                    \
        mv2 += w2 * se * Yv.w + w3 * v2 * Yv.x + w5 * cz;                    \
    } while (0)

// one 32-lane group per dst node; coalesced perm_src chunk + shfl broadcast;
// 2-edge straight-line unroll (no loop-carried state, no lambdas)
__global__ void agg_kernel(const int* __restrict__ base,
                           const int* __restrict__ perm_src,
                           const float* __restrict__ hS,
                           const float* __restrict__ YS,
                           const float* __restrict__ sv,
                           const float* __restrict__ Wr2,
                           float* __restrict__ agg) {
    __shared__ float wr2s[8][160];
    int t = threadIdx.x;
    for (int i = t; i < 8 * 160; i += 256) ((float*)wr2s)[i] = Wr2[i];
    __syncthreads();
    int n = blockIdx.x * 8 + (t >> 5);
    int c = t & 31;
    int jb = base[n], je = base[n + 1];
    float ms = 0.f, mv0 = 0.f, mv1 = 0.f, mv2 = 0.f;

    for (int j0 = jb; j0 < je; j0 += 32) {
        int myidx = j0 + c;
        int src_l = (myidx < je) ? perm_src[myidx] : 0;
        int cnt = min(32, je - j0);
        int i = 0;
        for (; i + 1 < cnt; i += 2) {
            int srcA = __shfl(src_l, i, 32);
            int srcB = __shfl(src_l, i + 1, 32);
            const float* pA = sv + (size_t)srcA * 128;
            const float* pB = sv + (size_t)srcB * 128;
            float seA = pA[c];
            float vA0 = pA[32 + c * 3 + 0];
            float vA1 = pA[32 + c * 3 + 1];
            float vA2 = pA[32 + c * 3 + 2];
            float seB = pB[c];
            float vB0 = pB[32 + c * 3 + 0];
            float vB1 = pB[32 + c * 3 + 1];
            float vB2 = pB[32 + c * 3 + 2];
            const float4* hA4 = (const float4*)(hS + (size_t)(j0 + i) * 8);
            float4 hAa = hA4[0], hAb = hA4[1];
            float4 YA = ((const float4*)YS)[j0 + i];
            const float4* hB4 = (const float4*)(hS + (size_t)(j0 + i + 1) * 8);
            float4 hBa = hB4[0], hBb = hB4[1];
            float4 YB = ((const float4*)YS)[j0 + i + 1];
            PROC_EDGE(hAa, hAb, YA, seA, vA0, vA1, vA2);
            PROC_EDGE(hBa, hBb, YB, seB, vB0, vB1, vB2);
        }
        if (i < cnt) {
            int srcA = __shfl(src_l, i, 32);
            const float* pA = sv + (size_t)srcA * 128;
            float seA = pA[c];
            float vA0 = pA[32 + c * 3 + 0];
            float vA1 = pA[32 + c * 3 + 1];
            float vA2 = pA[32 + c * 3 + 2];
            const float4* hA4 = (const float4*)(hS + (size_t)(j0 + i) * 8);
            float4 hAa = hA4[0], hAb = hA4[1];
            float4 YA = ((const float4*)YS)[j0 + i];
            PROC_EDGE(hAa, hAb, YA, seA, vA0, vA1, vA2);
        }
    }

    float* ap = agg + (size_t)n * 128;
    ap[c] = ms * DEG_INV;
    ap[32 + c * 3 + 0] = mv0 * DEG_INV;
    ap[32 + c * 3 + 1] = mv1 * DEG_INV;
    ap[32 + c * 3 + 2] = mv2 * DEG_INV;
}

// node_post, optionally fused with next layer's node_pre (WANT_SV=1)
template <int WANT_SV>
__global__ void post_pre_kernel(float* __restrict__ x,
                                const float* __restrict__ attrs,
                                const float* __restrict__ agg,
                                const float* __restrict__ Ws,
                                const float* __restrict__ Wv,
                                const float* __restrict__ Wsc_s,
                                const float* __restrict__ Wsc_v,
                                const float* __restrict__ W0n,   // next layer
                                const float* __restrict__ W1n,
                                float* __restrict__ sv) {
    __shared__ float shx[8][128];
    __shared__ float sha[8][128];
    int t = threadIdx.x;
    int node0 = blockIdx.x * 8;
    #pragma unroll
    for (int k = 0; k < 4; ++k) {
        int idx = t + k * 256;
        int n = idx >> 7, col = idx & 127;
        int gn = node0 + n;
        shx[n][col] = x[(size_t)gn * 128 + col];
        sha[n][col] = agg[(size_t)gn * 128 + col];
    }
    __syncthreads();
    int n = t >> 5, f = t & 31;
    int gn = node0 + n;

    float az0 = attrs[gn * 4 + 0], az1 = attrs[gn * 4 + 1];
    float az2 = attrs[gn * 4 + 2], az3 = attrs[gn * 4 + 3];

    float os0 = 0.f, os1 = 0.f;
    float ov0 = 0.f, ov1 = 0.f, ov2 = 0.f;

    #pragma unroll 4
    for (int c = 0; c < Cc; ++c) {
        float as = sha[n][c];
        os0 = fmaf(as, Ws[c * 64 + f], os0);
        os1 = fmaf(as, Ws[c * 64 + 32 + f], os1);

        float av0 = sha[n][32 + c * 3 + 0];
        float av1 = sha[n][32 + c * 3 + 1];
        float av2 = sha[n][32 + c * 3 + 2];
        float wv = Wv[c * 32 + f];
        ov0 = fmaf(av0, wv, ov0);
        ov1 = fmaf(av1, wv, ov1);
        ov2 = fmaf(av2, wv, ov2);

        float sc  = shx[n][c];
        float vi0 = shx[n][32 + c * 3 + 0];
        float vi1 = shx[n][32 + c * 3 + 1];
        float vi2 = shx[n][32 + c * 3 + 2];

        #pragma unroll
        for (int z = 0; z < 4; ++z) {
            float azv = (z == 0) ? az0 : (z == 1) ? az1 : (z == 2) ? az2 : az3;
            int cz = c * 4 + z;
            float sa = sc * azv;
            os0 = fmaf(sa, Wsc_s[cz * 64 + f], os0);
            os1 = fmaf(sa, Wsc_s[cz * 64 + 32 + f], os1);
            float va = azv * Wsc_v[cz * 32 + f];
            ov0 = fmaf(vi0, va, ov0);
            ov1 = fmaf(vi1, va, ov1);
            ov2 = fmaf(vi2, va, ov2);
        }
    }
    float feat = ssp_f(os0);
    float gate = ssp_f(os1);
    float ns  = shx[n][f] + feat;
    float nv0 = shx[n][32 + f * 3 + 0] + ov0 * gate;
    float nv1 = shx[n][32 + f * 3 + 1] + ov1 * gate;
    float nv2 = shx[n][32 + f * 3 + 2] + ov2 * gate;
    float* xp = x + (size_t)gn * 128;
    xp[f] = ns;
    xp[32 + f * 3 + 0] = nv0;
    xp[32 + f * 3 + 1] = nv1;
    xp[32 + f * 3 + 2] = nv2;

    if (WANT_SV) {
        __syncthreads();            // all reads of sha done
        sha[n][f] = ns;             // reuse sha as new-x buffer
        sha[n][32 + f * 3 + 0] = nv0;
        sha[n][32 + f * 3 + 1] = nv1;
        sha[n][32 + f * 3 + 2] = nv2;
        __syncthreads();
        float acc_s = 0.f, a0 = 0.f, a1 = 0.f, a2 = 0.f;
        #pragma unroll
        for (int c = 0; c < Cc; ++c) {
            float w0 = W0n[c * Cc + f];
            float w1 = W1n[c * Cc + f];
            acc_s = fmaf(sha[n][c], w0, acc_s);
            a0 = fmaf(sha[n][32 + c * 3 + 0], w1, a0);
            a1 = fmaf(sha[n][32 + c * 3 + 1], w1, a1);
            a2 = fmaf(sha[n][32 + c * 3 + 2], w1, a2);
        }
        float* o = sv + (size_t)gn * 128;
        o[f] = acc_s;
        o[32 + f * 3 + 0] = a0;
        o[32 + f * 3 + 1] = a1;
        o[32 + f * 3 + 2] = a2;
    }
}

// fallback (atomic) edge kernel
__global__ void edge_atomic_kernel(const int* __restrict__ ei,
                                   const float* __restrict__ emb,
                                   const float* __restrict__ eattr,
                                   const float* __restrict__ sv,
                                   const float* __restrict__ Wr1,
                                   const float* __restrict__ Wr2,
                                   float* __restrict__ agg) {
    int t = threadIdx.x;
    int eg = t >> 5;
    int c = t & 31;
    int e = blockIdx.x * 8 + eg;
    if (e >= NE) return;
    int src = ei[e];
    int dst = ei[NE + e];
    float h = 0.f;
    if (c < 8) {
        #pragma unroll
        for (int k = 0; k < 8; ++k)
            h = fmaf(emb[e * 8 + k], Wr1[k * 8 + c], h);
        h = silu_f(h);
    }
    float w1 = 0.f, w2 = 0.f, w3 = 0.f, w4 = 0.f, w5 = 0.f;
    #pragma unroll
    for (int j = 0; j < 8; ++j) {
        float hj = __shfl(h, j, 32);
        const float* wr = Wr2 + j * 160;
        w1 = fmaf(hj, wr[c], w1);
        w2 = fmaf(hj, wr[32 + c], w2);
        w3 = fmaf(hj, wr[64 + c], w3);
        w4 = fmaf(hj, wr[96 + c], w4);
        w5 = fmaf(hj, wr[128 + c], w5);
    }
    float Y0  = eattr[e * 4 + 0];
    float Yv0 = eattr[e * 4 + 1];
    float Yv1 = eattr[e * 4 + 2];
    float Yv2 = eattr[e * 4 + 3];
    const float* svp = sv + (size_t)src * 128;
    float se  = svp[c];
    float ve0 = svp[32 + c * 3 + 0];
    float ve1 = svp[32 + c * 3 + 1];
    float ve2 = svp[32 + c * 3 + 2];
    float dot = ve0 * Yv0 + ve1 * Yv1 + ve2 * Yv2;
    float msg = (w1 * se * Y0 + w4 * dot) * DEG_INV;
    float cx = ve1 * Yv2 - ve2 * Yv1;
    float cy = ve2 * Yv0 - ve0 * Yv2;
    float cz = ve0 * Yv1 - ve1 * Yv0;
    float mv0 = (w2 * se * Yv0 + w3 * ve0 * Y0 + w5 * cx) * DEG_INV;
    float mv1 = (w2 * se * Yv1 + w3 * ve1 * Y0 + w5 * cy) * DEG_INV;
    float mv2 = (w2 * se * Yv2 + w3 * ve2 * Y0 + w5 * cz) * DEG_INV;
    float* ap = agg + (size_t)dst * 128;
    atomicAdd(&ap[c], msg);
    atomicAdd(&ap[32 + c * 3 + 0], mv0);
    atomicAdd(&ap[32 + c * 3 + 1], mv1);
    atomicAdd(&ap[32 + c * 3 + 2], mv2);
}

extern "C" void kernel_launch(void* const* d_in, const int* in_sizes, int n_in,
                              void* d_out, int out_size, void* d_ws, size_t ws_size,
                              hipStream_t stream) {
    const float* node_features  = (const float*)d_in[0];
    const float* node_attrs     = (const float*)d_in[1];
    const int*   edge_index     = (const int*)d_in[2];
    const float* edge_embedding = (const float*)d_in[3];
    const float* edge_attrs     = (const float*)d_in[4];
    const float* W0    = (const float*)d_in[5];
    const float* W1    = (const float*)d_in[6];
    const float* Wr1   = (const float*)d_in[7];
    const float* Wr2   = (const float*)d_in[8];
    const float* Ws    = (const float*)d_in[9];
    const float* Wv    = (const float*)d_in[10];
    const float* Wsc_s = (const float*)d_in[11];
    const float* Wsc_v = (const float*)d_in[12];

    float* x = (float*)d_out;

    // float arrays first (16B alignment for float4), then int arrays
    float* ws = (float*)d_ws;
    float* sv   = ws;                                 // NN*128
    float* agg  = sv + (size_t)NN * 128;              // NN*128
    float* hS0  = agg + (size_t)NN * 128;             // NE*8
    float* hS1  = hS0 + (size_t)NE * 8;               // NE*8
    float* YS   = hS1 + (size_t)NE * 8;               // NE*4
    int* counts   = (int*)(YS + (size_t)NE * 4);      // SCAN_PAD
    int* base     = counts + SCAN_PAD;                // NN+1
    int* cursor   = base + NN + 1;                    // NN
    int* perm_src = cursor + NN;                      // NE
    size_t needed = ((char*)(perm_src + NE)) - (char*)d_ws;

    bool use_sorted = ws_size >= needed;

    if (use_sorted) {
        hipMemsetAsync(counts, 0, SCAN_PAD * sizeof(int), stream);
        hist_kernel<<<NE / 256, 256, 0, stream>>>(edge_index, counts);
        scan_kernel<<<1, 1024, 0, stream>>>(counts, base, cursor);
        scatter_h_kernel<<<NE / 256, 256, 0, stream>>>(
            edge_index, edge_embedding, edge_attrs, Wr1,
            cursor, perm_src, hS0, hS1, YS);

        init_kernel<<<NN / 8, 256, 0, stream>>>(node_features, W0, W1, x, sv);

        // layer 0
        agg_kernel<<<NN / 8, 256, 0, stream>>>(base, perm_src, hS0, YS, sv,
                                               Wr2, agg);
        post_pre_kernel<1><<<NN / 8, 256, 0, stream>>>(
            x, node_attrs, agg, Ws, Wv, Wsc_s, Wsc_v,
            W0 + Cc * Cc, W1 + Cc * Cc, sv);
        // layer 1
        agg_kernel<<<NN / 8, 256, 0, stream>>>(base, perm_src, hS1, YS, sv,
                                               Wr2 + Bb * 5 * Cc, agg);
        post_pre_kernel<0><<<NN / 8, 256, 0, stream>>>(
            x, node_attrs, agg,
            Ws + Cc * 2 * Cc, Wv + Cc * Cc,
            Wsc_s + Cc * Zz * 2 * Cc, Wsc_v + Cc * Zz * Cc,
            nullptr, nullptr, nullptr);
    } else {
        hipMemcpyAsync(x, node_features, (size_t)NN * 128 * sizeof(float),
                       hipMemcpyDeviceToDevice, stream);
        for (int l = 0; l < NL; ++l) {
            hipMemsetAsync(agg, 0, (size_t)NN * 128 * sizeof(float), stream);
            init_kernel<<<NN / 8, 256, 0, stream>>>(
                x, W0 + l * Cc * Cc, W1 + l * Cc * Cc, x, sv);
            edge_atomic_kernel<<<NE / 8, 256, 0, stream>>>(
                edge_index, edge_embedding, edge_attrs, sv,
                Wr1 + l * Bb * Bb, Wr2 + l * Bb * 5 * Cc, agg);
            post_pre_kernel<0><<<NN / 8, 256, 0, stream>>>(
                x, node_attrs, agg,
                Ws + l * Cc * 2 * Cc, Wv + l * Cc * Cc,
                Wsc_s + l * Cc * Zz * 2 * Cc, Wsc_v + l * Cc * Zz * Cc,
                nullptr, nullptr, nullptr);
        }
    }
}

// Round 6
// 546.939 us; speedup vs baseline: 2.1617x; 1.1018x over previous
//
#include <hip/hip_runtime.h>
#include <math.h>

#define NN 50000
#define NE 800000
#define Cc 32
#define Zz 4
#define Bb 8
#define NL 2
#define DEG_INV (1.0f/16.0f)
#define SCAN_PAD 53248  // 1024 * 52

__device__ __forceinline__ float ssp_f(float x) {
    float sp = fmaxf(x, 0.0f) + log1pf(expf(-fabsf(x)));
    return sp - 0.69314718055994530942f;
}
__device__ __forceinline__ float silu_f(float x) {
    return x / (1.0f + expf(-x));
}

// ---------------- CSR build (once per call) ----------------

__global__ void hist_kernel(const int* __restrict__ ei, int* __restrict__ counts) {
    int e = blockIdx.x * 256 + threadIdx.x;
    if (e < NE) atomicAdd(&counts[ei[NE + e]], 1);
}

// 1 block, 1024 threads: exclusive scan of counts[] -> base[NN+1], copy to cursor
__global__ void scan_kernel(const int* __restrict__ counts,
                            int* __restrict__ base,
                            int* __restrict__ cursor) {
    __shared__ int partial[1024];
    int t = threadIdx.x;
    const int CH = 52;
    int b0 = t * CH;
    int sum = 0;
    #pragma unroll
    for (int i = 0; i < CH; i += 4) {
        int4 v = *(const int4*)(counts + b0 + i);
        sum += v.x + v.y + v.z + v.w;
    }
    partial[t] = sum;
    __syncthreads();
    for (int off = 1; off < 1024; off <<= 1) {
        int v = 0;
        if (t >= off) v = partial[t - off];
        __syncthreads();
        if (t >= off) partial[t] += v;
        __syncthreads();
    }
    int prefix = (t == 0) ? 0 : partial[t - 1];
    for (int i = b0; i < b0 + CH && i < NN; ++i) {
        base[i] = prefix;
        cursor[i] = prefix;
        prefix += counts[i];
    }
    if (t == 1023) base[NN] = partial[1023];
}

// fused scatter + permute + h-precompute (both layers).
__global__ void scatter_h_kernel(const int* __restrict__ ei,
                                 const float* __restrict__ emb,
                                 const float* __restrict__ eattr,
                                 const float* __restrict__ Wr1,   // [2][8][8]
                                 int* __restrict__ cursor,
                                 int* __restrict__ perm_src,
                                 float* __restrict__ hS0,
                                 float* __restrict__ hS1,
                                 float* __restrict__ YS) {
    __shared__ float wr1s[2][64];
    int t = threadIdx.x;
    if (t < 128) ((float*)wr1s)[t] = Wr1[t];
    __syncthreads();
    int e = blockIdx.x * 256 + t;
    if (e >= NE) return;
    int dst = ei[NE + e];
    int pos = atomicAdd(&cursor[dst], 1);
    perm_src[pos] = ei[e];

    const float4* s4 = (const float4*)emb + (size_t)e * 2;
    float4 a = s4[0], b = s4[1];
    float em[8] = {a.x, a.y, a.z, a.w, b.x, b.y, b.z, b.w};
    float h0[8], h1[8];
    #pragma unroll
    for (int j = 0; j < 8; ++j) {
        float acc0 = 0.f, acc1 = 0.f;
        #pragma unroll
        for (int k = 0; k < 8; ++k) {
            acc0 = fmaf(em[k], wr1s[0][k * 8 + j], acc0);
            acc1 = fmaf(em[k], wr1s[1][k * 8 + j], acc1);
        }
        h0[j] = silu_f(acc0);
        h1[j] = silu_f(acc1);
    }
    float4* o0 = (float4*)(hS0 + (size_t)pos * 8);
    o0[0] = make_float4(h0[0], h0[1], h0[2], h0[3]);
    o0[1] = make_float4(h0[4], h0[5], h0[6], h0[7]);
    float4* o1 = (float4*)(hS1 + (size_t)pos * 8);
    o1[0] = make_float4(h1[0], h1[1], h1[2], h1[3]);
    o1[1] = make_float4(h1[4], h1[5], h1[6], h1[7]);
    ((float4*)YS)[pos] = ((const float4*)eattr)[e];
}

// ---------------- per-layer kernels ----------------

// fused: x = node_features (copy) + sv = pre(x)
__global__ void init_kernel(const float* __restrict__ nf,
                            const float* __restrict__ W0,
                            const float* __restrict__ W1,
                            float* __restrict__ x,
                            float* __restrict__ sv) {
    __shared__ float xs[8][128];
    int t = threadIdx.x;
    int node0 = blockIdx.x * 8;
    #pragma unroll
    for (int k = 0; k < 4; ++k) {
        int idx = t + k * 256;
        int n = idx >> 7, col = idx & 127;
        float val = nf[(size_t)(node0 + n) * 128 + col];
        xs[n][col] = val;
        x[(size_t)(node0 + n) * 128 + col] = val;
    }
    __syncthreads();
    int n = t >> 5, f = t & 31;
    int gn = node0 + n;
    float acc_s = 0.f, a0 = 0.f, a1 = 0.f, a2 = 0.f;
    #pragma unroll
    for (int c = 0; c < Cc; ++c) {
        float w0 = W0[c * Cc + f];
        float w1 = W1[c * Cc + f];
        acc_s = fmaf(xs[n][c], w0, acc_s);
        a0 = fmaf(xs[n][32 + c * 3 + 0], w1, a0);
        a1 = fmaf(xs[n][32 + c * 3 + 1], w1, a1);
        a2 = fmaf(xs[n][32 + c * 3 + 2], w1, a2);
    }
    float* o = sv + (size_t)gn * 128;
    o[f] = acc_s;
    o[32 + f * 3 + 0] = a0;
    o[32 + f * 3 + 1] = a1;
    o[32 + f * 3 + 2] = a2;
}

#define PROC_EDGE(ha, hb, Yv, se, v0, v1, v2)                                \
    do {                                                                     \
        float hh0 = ha.x, hh1 = ha.y, hh2 = ha.z, hh3 = ha.w;                \
        float hh4 = hb.x, hh5 = hb.y, hh6 = hb.z, hh7 = hb.w;                \
        float w1 = 0.f, w2 = 0.f, w3 = 0.f, w4 = 0.f, w5 = 0.f;              \
        w1 = fmaf(hh0, wr2s[0][c], w1); w2 = fmaf(hh0, wr2s[0][32 + c], w2); \
        w3 = fmaf(hh0, wr2s[0][64 + c], w3); w4 = fmaf(hh0, wr2s[0][96 + c], w4); \
        w5 = fmaf(hh0, wr2s[0][128 + c], w5);                                \
        w1 = fmaf(hh1, wr2s[1][c], w1); w2 = fmaf(hh1, wr2s[1][32 + c], w2); \
        w3 = fmaf(hh1, wr2s[1][64 + c], w3); w4 = fmaf(hh1, wr2s[1][96 + c], w4); \
        w5 = fmaf(hh1, wr2s[1][128 + c], w5);                                \
        w1 = fmaf(hh2, wr2s[2][c], w1); w2 = fmaf(hh2, wr2s[2][32 + c], w2); \
        w3 = fmaf(hh2, wr2s[2][64 + c], w3); w4 = fmaf(hh2, wr2s[2][96 + c], w4); \
        w5 = fmaf(hh2, wr2s[2][128 + c], w5);                                \
        w1 = fmaf(hh3, wr2s[3][c], w1); w2 = fmaf(hh3, wr2s[3][32 + c], w2); \
        w3 = fmaf(hh3, wr2s[3][64 + c], w3); w4 = fmaf(hh3, wr2s[3][96 + c], w4); \
        w5 = fmaf(hh3, wr2s[3][128 + c], w5);                                \
        w1 = fmaf(hh4, wr2s[4][c], w1); w2 = fmaf(hh4, wr2s[4][32 + c], w2); \
        w3 = fmaf(hh4, wr2s[4][64 + c], w3); w4 = fmaf(hh4, wr2s[4][96 + c], w4); \
        w5 = fmaf(hh4, wr2s[4][128 + c], w5);                                \
        w1 = fmaf(hh5, wr2s[5][c], w1); w2 = fmaf(hh5, wr2s[5][32 + c], w2); \
        w3 = fmaf(hh5, wr2s[5][64 + c], w3); w4 = fmaf(hh5, wr2s[5][96 + c], w4); \
        w5 = fmaf(hh5, wr2s[5][128 + c], w5);                                \
        w1 = fmaf(hh6, wr2s[6][c], w1); w2 = fmaf(hh6, wr2s[6][32 + c], w2); \
        w3 = fmaf(hh6, wr2s[6][64 + c], w3); w4 = fmaf(hh6, wr2s[6][96 + c], w4); \
        w5 = fmaf(hh6, wr2s[6][128 + c], w5);                                \
        w1 = fmaf(hh7, wr2s[7][c], w1); w2 = fmaf(hh7, wr2s[7][32 + c], w2); \
        w3 = fmaf(hh7, wr2s[7][64 + c], w3); w4 = fmaf(hh7, wr2s[7][96 + c], w4); \
        w5 = fmaf(hh7, wr2s[7][128 + c], w5);                                \
        float dot = v0 * Yv.y + v1 * Yv.z + v2 * Yv.w;                       \
        ms += w1 * se * Yv.x + w4 * dot;                                     \
        float cx = v1 * Yv.w - v2 * Yv.z;                                    \
        float cy = v2 * Yv.y - v0 * Yv.w;                                    \
        float cz = v0 * Yv.z - v1 * Yv.y;                                    \
        mv0 += w2 * se * Yv.y + w3 * v0 * Yv.x + w5 * cx;                    \
        mv1 += w2 * se * Yv.z + w3 * v1 * Yv.x + w5 * cy;                    \
        mv2 += w2 * se * Yv.w + w3 * v2 * Yv.x + w5 * cz;                    \
    } while (0)

// one 32-lane group per dst node; coalesced perm_src chunk + shfl broadcast;
// 2-edge straight-line unroll (no loop-carried state, no lambdas)
__global__ void agg_kernel(const int* __restrict__ base,
                           const int* __restrict__ perm_src,
                           const float* __restrict__ hS,
                           const float* __restrict__ YS,
                           const float* __restrict__ sv,
                           const float* __restrict__ Wr2,
                           float* __restrict__ agg) {
    __shared__ float wr2s[8][160];
    int t = threadIdx.x;
    for (int i = t; i < 8 * 160; i += 256) ((float*)wr2s)[i] = Wr2[i];
    __syncthreads();
    int n = blockIdx.x * 8 + (t >> 5);
    int c = t & 31;
    int jb = base[n], je = base[n + 1];
    float ms = 0.f, mv0 = 0.f, mv1 = 0.f, mv2 = 0.f;

    for (int j0 = jb; j0 < je; j0 += 32) {
        int myidx = j0 + c;
        int src_l = (myidx < je) ? perm_src[myidx] : 0;
        int cnt = min(32, je - j0);
        int i = 0;
        for (; i + 1 < cnt; i += 2) {
            int srcA = __shfl(src_l, i, 32);
            int srcB = __shfl(src_l, i + 1, 32);
            const float* pA = sv + (size_t)srcA * 128;
            const float* pB = sv + (size_t)srcB * 128;
            float seA = pA[c];
            float vA0 = pA[32 + c * 3 + 0];
            float vA1 = pA[32 + c * 3 + 1];
            float vA2 = pA[32 + c * 3 + 2];
            float seB = pB[c];
            float vB0 = pB[32 + c * 3 + 0];
            float vB1 = pB[32 + c * 3 + 1];
            float vB2 = pB[32 + c * 3 + 2];
            const float4* hA4 = (const float4*)(hS + (size_t)(j0 + i) * 8);
            float4 hAa = hA4[0], hAb = hA4[1];
            float4 YA = ((const float4*)YS)[j0 + i];
            const float4* hB4 = (const float4*)(hS + (size_t)(j0 + i + 1) * 8);
            float4 hBa = hB4[0], hBb = hB4[1];
            float4 YB = ((const float4*)YS)[j0 + i + 1];
            PROC_EDGE(hAa, hAb, YA, seA, vA0, vA1, vA2);
            PROC_EDGE(hBa, hBb, YB, seB, vB0, vB1, vB2);
        }
        if (i < cnt) {
            int srcA = __shfl(src_l, i, 32);
            const float* pA = sv + (size_t)srcA * 128;
            float seA = pA[c];
            float vA0 = pA[32 + c * 3 + 0];
            float vA1 = pA[32 + c * 3 + 1];
            float vA2 = pA[32 + c * 3 + 2];
            const float4* hA4 = (const float4*)(hS + (size_t)(j0 + i) * 8);
            float4 hAa = hA4[0], hAb = hA4[1];
            float4 YA = ((const float4*)YS)[j0 + i];
            PROC_EDGE(hAa, hAb, YA, seA, vA0, vA1, vA2);
        }
    }

    float* ap = agg + (size_t)n * 128;
    ap[c] = ms * DEG_INV;
    ap[32 + c * 3 + 0] = mv0 * DEG_INV;
    ap[32 + c * 3 + 1] = mv1 * DEG_INV;
    ap[32 + c * 3 + 2] = mv2 * DEG_INV;
}

// node_post (+ optional next-layer node_pre), 32 nodes/block, 4 nodes/thread:
// every weight load feeds 4 nodes' FMAs.
template <int WANT_SV>
__global__ void post_pre_kernel(float* __restrict__ x,
                                const float* __restrict__ attrs,
                                const float* __restrict__ agg,
                                const float* __restrict__ Ws,
                                const float* __restrict__ Wv,
                                const float* __restrict__ Wsc_s,
                                const float* __restrict__ Wsc_v,
                                const float* __restrict__ W0n,   // next layer
                                const float* __restrict__ W1n,
                                float* __restrict__ sv) {
    __shared__ float shx[32][128];
    __shared__ float sha[32][128];
    int t = threadIdx.x;
    int node0 = blockIdx.x * 32;
    #pragma unroll
    for (int k = 0; k < 4; ++k) {
        int f4 = t + k * 256;          // 0..1023 float4 slots
        int n = f4 >> 5, col4 = f4 & 31;
        int gn = node0 + n;
        if (gn < NN) {
            ((float4*)&shx[n][0])[col4] = ((const float4*)(x + (size_t)gn * 128))[col4];
            ((float4*)&sha[n][0])[col4] = ((const float4*)(agg + (size_t)gn * 128))[col4];
        }
    }
    __syncthreads();
    int g = t >> 5, f = t & 31;

    float az[4][4];
    #pragma unroll
    for (int k = 0; k < 4; ++k) {
        int gn = node0 + g + k * 8;
        if (gn < NN) {
            float4 a4 = ((const float4*)attrs)[gn];
            az[k][0] = a4.x; az[k][1] = a4.y; az[k][2] = a4.z; az[k][3] = a4.w;
        } else {
            az[k][0] = az[k][1] = az[k][2] = az[k][3] = 0.f;
        }
    }

    float os0[4] = {0, 0, 0, 0}, os1[4] = {0, 0, 0, 0};
    float ov0[4] = {0, 0, 0, 0}, ov1[4] = {0, 0, 0, 0}, ov2[4] = {0, 0, 0, 0};

    #pragma unroll 2
    for (int c = 0; c < Cc; ++c) {
        float ws0 = Ws[c * 64 + f];
        float ws1 = Ws[c * 64 + 32 + f];
        float wv  = Wv[c * 32 + f];
        #pragma unroll
        for (int k = 0; k < 4; ++k) {
            int n = g + k * 8;
            float as  = sha[n][c];
            float av0 = sha[n][32 + c * 3 + 0];
            float av1 = sha[n][32 + c * 3 + 1];
            float av2 = sha[n][32 + c * 3 + 2];
            os0[k] = fmaf(as, ws0, os0[k]);
            os1[k] = fmaf(as, ws1, os1[k]);
            ov0[k] = fmaf(av0, wv, ov0[k]);
            ov1[k] = fmaf(av1, wv, ov1[k]);
            ov2[k] = fmaf(av2, wv, ov2[k]);
        }
        #pragma unroll
        for (int z = 0; z < 4; ++z) {
            int cz = c * 4 + z;
            float wss0 = Wsc_s[cz * 64 + f];
            float wss1 = Wsc_s[cz * 64 + 32 + f];
            float wsv  = Wsc_v[cz * 32 + f];
            #pragma unroll
            for (int k = 0; k < 4; ++k) {
                int n = g + k * 8;
                float azv = az[k][z];
                float sa = shx[n][c] * azv;
                os0[k] = fmaf(sa, wss0, os0[k]);
                os1[k] = fmaf(sa, wss1, os1[k]);
                float va = azv * wsv;
                ov0[k] = fmaf(shx[n][32 + c * 3 + 0], va, ov0[k]);
                ov1[k] = fmaf(shx[n][32 + c * 3 + 1], va, ov1[k]);
                ov2[k] = fmaf(shx[n][32 + c * 3 + 2], va, ov2[k]);
            }
        }
    }

    float ns[4], nv0[4], nv1[4], nv2[4];
    #pragma unroll
    for (int k = 0; k < 4; ++k) {
        int n = g + k * 8;
        int gn = node0 + n;
        float feat = ssp_f(os0[k]);
        float gate = ssp_f(os1[k]);
        ns[k]  = shx[n][f] + feat;
        nv0[k] = shx[n][32 + f * 3 + 0] + ov0[k] * gate;
        nv1[k] = shx[n][32 + f * 3 + 1] + ov1[k] * gate;
        nv2[k] = shx[n][32 + f * 3 + 2] + ov2[k] * gate;
        if (gn < NN) {
            float* xp = x + (size_t)gn * 128;
            xp[f] = ns[k];
            xp[32 + f * 3 + 0] = nv0[k];
            xp[32 + f * 3 + 1] = nv1[k];
            xp[32 + f * 3 + 2] = nv2[k];
        }
    }

    if (WANT_SV) {
        __syncthreads();            // all reads of sha/shx done
        #pragma unroll
        for (int k = 0; k < 4; ++k) {
            int n = g + k * 8;
            sha[n][f] = ns[k];      // reuse sha as new-x buffer
            sha[n][32 + f * 3 + 0] = nv0[k];
            sha[n][32 + f * 3 + 1] = nv1[k];
            sha[n][32 + f * 3 + 2] = nv2[k];
        }
        __syncthreads();
        float bs[4] = {0, 0, 0, 0};
        float b0[4] = {0, 0, 0, 0}, b1[4] = {0, 0, 0, 0}, b2[4] = {0, 0, 0, 0};
        #pragma unroll 4
        for (int c = 0; c < Cc; ++c) {
            float w0 = W0n[c * Cc + f];
            float w1 = W1n[c * Cc + f];
            #pragma unroll
            for (int k = 0; k < 4; ++k) {
                int n = g + k * 8;
                bs[k] = fmaf(sha[n][c], w0, bs[k]);
                b0[k] = fmaf(sha[n][32 + c * 3 + 0], w1, b0[k]);
                b1[k] = fmaf(sha[n][32 + c * 3 + 1], w1, b1[k]);
                b2[k] = fmaf(sha[n][32 + c * 3 + 2], w1, b2[k]);
            }
        }
        #pragma unroll
        for (int k = 0; k < 4; ++k) {
            int gn = node0 + g + k * 8;
            if (gn < NN) {
                float* o = sv + (size_t)gn * 128;
                o[f] = bs[k];
                o[32 + f * 3 + 0] = b0[k];
                o[32 + f * 3 + 1] = b1[k];
                o[32 + f * 3 + 2] = b2[k];
            }
        }
    }
}

// fallback (atomic) edge kernel
__global__ void edge_atomic_kernel(const int* __restrict__ ei,
                                   const float* __restrict__ emb,
                                   const float* __restrict__ eattr,
                                   const float* __restrict__ sv,
                                   const float* __restrict__ Wr1,
                                   const float* __restrict__ Wr2,
                                   float* __restrict__ agg) {
    int t = threadIdx.x;
    int eg = t >> 5;
    int c = t & 31;
    int e = blockIdx.x * 8 + eg;
    if (e >= NE) return;
    int src = ei[e];
    int dst = ei[NE + e];
    float h = 0.f;
    if (c < 8) {
        #pragma unroll
        for (int k = 0; k < 8; ++k)
            h = fmaf(emb[e * 8 + k], Wr1[k * 8 + c], h);
        h = silu_f(h);
    }
    float w1 = 0.f, w2 = 0.f, w3 = 0.f, w4 = 0.f, w5 = 0.f;
    #pragma unroll
    for (int j = 0; j < 8; ++j) {
        float hj = __shfl(h, j, 32);
        const float* wr = Wr2 + j * 160;
        w1 = fmaf(hj, wr[c], w1);
        w2 = fmaf(hj, wr[32 + c], w2);
        w3 = fmaf(hj, wr[64 + c], w3);
        w4 = fmaf(hj, wr[96 + c], w4);
        w5 = fmaf(hj, wr[128 + c], w5);
    }
    float Y0  = eattr[e * 4 + 0];
    float Yv0 = eattr[e * 4 + 1];
    float Yv1 = eattr[e * 4 + 2];
    float Yv2 = eattr[e * 4 + 3];
    const float* svp = sv + (size_t)src * 128;
    float se  = svp[c];
    float ve0 = svp[32 + c * 3 + 0];
    float ve1 = svp[32 + c * 3 + 1];
    float ve2 = svp[32 + c * 3 + 2];
    float dot = ve0 * Yv0 + ve1 * Yv1 + ve2 * Yv2;
    float msg = (w1 * se * Y0 + w4 * dot) * DEG_INV;
    float cx = ve1 * Yv2 - ve2 * Yv1;
    float cy = ve2 * Yv0 - ve0 * Yv2;
    float cz = ve0 * Yv1 - ve1 * Yv0;
    float mv0 = (w2 * se * Yv0 + w3 * ve0 * Y0 + w5 * cx) * DEG_INV;
    float mv1 = (w2 * se * Yv1 + w3 * ve1 * Y0 + w5 * cy) * DEG_INV;
    float mv2 = (w2 * se * Yv2 + w3 * ve2 * Y0 + w5 * cz) * DEG_INV;
    float* ap = agg + (size_t)dst * 128;
    atomicAdd(&ap[c], msg);
    atomicAdd(&ap[32 + c * 3 + 0], mv0);
    atomicAdd(&ap[32 + c * 3 + 1], mv1);
    atomicAdd(&ap[32 + c * 3 + 2], mv2);
}

extern "C" void kernel_launch(void* const* d_in, const int* in_sizes, int n_in,
                              void* d_out, int out_size, void* d_ws, size_t ws_size,
                              hipStream_t stream) {
    const float* node_features  = (const float*)d_in[0];
    const float* node_attrs     = (const float*)d_in[1];
    const int*   edge_index     = (const int*)d_in[2];
    const float* edge_embedding = (const float*)d_in[3];
    const float* edge_attrs     = (const float*)d_in[4];
    const float* W0    = (const float*)d_in[5];
    const float* W1    = (const float*)d_in[6];
    const float* Wr1   = (const float*)d_in[7];
    const float* Wr2   = (const float*)d_in[8];
    const float* Ws    = (const float*)d_in[9];
    const float* Wv    = (const float*)d_in[10];
    const float* Wsc_s = (const float*)d_in[11];
    const float* Wsc_v = (const float*)d_in[12];

    float* x = (float*)d_out;

    // float arrays first (16B alignment for float4), then int arrays
    float* ws = (float*)d_ws;
    float* sv   = ws;                                 // NN*128
    float* agg  = sv + (size_t)NN * 128;              // NN*128
    float* hS0  = agg + (size_t)NN * 128;             // NE*8
    float* hS1  = hS0 + (size_t)NE * 8;               // NE*8
    float* YS   = hS1 + (size_t)NE * 8;               // NE*4
    int* counts   = (int*)(YS + (size_t)NE * 4);      // SCAN_PAD
    int* base     = counts + SCAN_PAD;                // NN+1
    int* cursor   = base + NN + 1;                    // NN
    int* perm_src = cursor + NN;                      // NE
    size_t needed = ((char*)(perm_src + NE)) - (char*)d_ws;

    bool use_sorted = ws_size >= needed;
    const int PP_GRID = (NN + 31) / 32;

    if (use_sorted) {
        hipMemsetAsync(counts, 0, SCAN_PAD * sizeof(int), stream);
        hist_kernel<<<NE / 256, 256, 0, stream>>>(edge_index, counts);
        scan_kernel<<<1, 1024, 0, stream>>>(counts, base, cursor);
        scatter_h_kernel<<<NE / 256, 256, 0, stream>>>(
            edge_index, edge_embedding, edge_attrs, Wr1,
            cursor, perm_src, hS0, hS1, YS);

        init_kernel<<<NN / 8, 256, 0, stream>>>(node_features, W0, W1, x, sv);

        // layer 0
        agg_kernel<<<NN / 8, 256, 0, stream>>>(base, perm_src, hS0, YS, sv,
                                               Wr2, agg);
        post_pre_kernel<1><<<PP_GRID, 256, 0, stream>>>(
            x, node_attrs, agg, Ws, Wv, Wsc_s, Wsc_v,
            W0 + Cc * Cc, W1 + Cc * Cc, sv);
        // layer 1
        agg_kernel<<<NN / 8, 256, 0, stream>>>(base, perm_src, hS1, YS, sv,
                                               Wr2 + Bb * 5 * Cc, agg);
        post_pre_kernel<0><<<PP_GRID, 256, 0, stream>>>(
            x, node_attrs, agg,
            Ws + Cc * 2 * Cc, Wv + Cc * Cc,
            Wsc_s + Cc * Zz * 2 * Cc, Wsc_v + Cc * Zz * Cc,
            nullptr, nullptr, nullptr);
    } else {
        hipMemcpyAsync(x, node_features, (size_t)NN * 128 * sizeof(float),
                       hipMemcpyDeviceToDevice, stream);
        for (int l = 0; l < NL; ++l) {
            hipMemsetAsync(agg, 0, (size_t)NN * 128 * sizeof(float), stream);
            init_kernel<<<NN / 8, 256, 0, stream>>>(
                x, W0 + l * Cc * Cc, W1 + l * Cc * Cc, x, sv);
            edge_atomic_kernel<<<NE / 8, 256, 0, stream>>>(
                edge_index, edge_embedding, edge_attrs, sv,
                Wr1 + l * Bb * Bb, Wr2 + l * Bb * 5 * Cc, agg);
            post_pre_kernel<0><<<PP_GRID, 256, 0, stream>>>(
                x, node_attrs, agg,
                Ws + l * Cc * 2 * Cc, Wv + l * Cc * Cc,
                Wsc_s + l * Cc * Zz * 2 * Cc, Wsc_v + l * Cc * Zz * Cc,
                nullptr, nullptr, nullptr);
        }
    }
}